// Round 3
// baseline (365.885 us; speedup 1.0000x reference)
//
#include <hip/hip_runtime.h>

typedef __attribute__((ext_vector_type(8))) unsigned short ushort8v;
typedef __attribute__((ext_vector_type(8))) short short8v;
typedef __attribute__((ext_vector_type(4))) float f32x4;

__device__ inline unsigned short f2bf(float f) {
    union { float f; unsigned u; } v; v.f = f;
    unsigned u = v.u;
    unsigned r = (u + 0x7FFFu + ((u >> 16) & 1u)) >> 16;
    return (unsigned short)r;
}
__device__ inline float bf2f(unsigned short h) {
    union { unsigned u; float f; } v; v.u = ((unsigned)h) << 16;
    return v.f;
}

// ---------------------------------------------------------------------------
// Fused pre-pass: [0, cvtB)   feat f32 -> X2 cols 128..255 bf16
//                 [cvtB, +histB) dst histogram, 4 edges/thread (int4, ILP)
//                 [cvtB+histB, +256) weight prep (W1t 256x128, W3t 128x256)
// ---------------------------------------------------------------------------
__global__ __launch_bounds__(256) void fused_pre(
    const float* __restrict__ feat, unsigned short* __restrict__ X2, int totalF,
    const int* __restrict__ dst, int* __restrict__ cnt, int E,
    const float* __restrict__ W1, const float* __restrict__ W2,
    const float* __restrict__ LW,
    unsigned short* __restrict__ W1t, unsigned short* __restrict__ W3t,
    int cvtB, int histB) {
    int b = blockIdx.x, t = threadIdx.x;
    if (b < cvtB) {
        int idx = (b * 256 + t) * 4;
        if (idx >= totalF) return;
        float4 v = *(const float4*)(feat + idx);
        int row = idx >> 7, col = idx & 127;
        unsigned short* o = X2 + (size_t)row * 256 + 128 + col;
        *(ushort4*)o = make_ushort4(f2bf(v.x), f2bf(v.y), f2bf(v.z), f2bf(v.w));
    } else if (b < cvtB + histB) {
        int e = ((b - cvtB) * 256 + t) * 4;
        if (e + 3 < E) {
            int4 d4 = *(const int4*)(dst + e);
            atomicAdd(&cnt[d4.x], 1);
            atomicAdd(&cnt[d4.y], 1);
            atomicAdd(&cnt[d4.z], 1);
            atomicAdd(&cnt[d4.w], 1);
        } else {
            for (int i = e; i < E; i++) atomicAdd(&cnt[dst[i]], 1);
        }
    } else {
        int i = (b - cvtB - histB) * 256 + t;  // 0..65535
        if (i < 32768) {
            int jj = i >> 7, k = i & 127;
            float v = (jj < 128) ? W1[k * 128 + jj] : W1[(128 + k) * 128 + (jj - 128)];
            W1t[i] = f2bf(v);
        } else {
            int i2 = i - 32768;
            int n = i2 >> 8, k = i2 & 255;
            float v = (k < 128) ? W2[k * 128 + n] : LW[(k - 128) * 128 + n];
            W3t[i2] = f2bf(v);
        }
    }
}

// ---------------------------------------------------------------------------
// Single-block exclusive scan of cnt[N] -> offs, cur. 1024 thr, 49 elems each.
// ---------------------------------------------------------------------------
__global__ __launch_bounds__(1024) void scan_kernel(
    const int* __restrict__ cnt, int* __restrict__ offs, int* __restrict__ cur, int N) {
    __shared__ int l[1024];
    int t = threadIdx.x;
    int per = (N + 1023) / 1024;
    int base = t * per;
    int s = 0;
    for (int i = 0; i < per; i++) {
        int idx = base + i;
        if (idx < N) s += cnt[idx];
    }
    l[t] = s;
    __syncthreads();
    for (int o = 1; o < 1024; o <<= 1) {
        int v = (t >= o) ? l[t - o] : 0;
        __syncthreads();
        l[t] += v;
        __syncthreads();
    }
    int excl = l[t] - s;
    for (int i = 0; i < per; i++) {
        int idx = base + i;
        if (idx < N) {
            int c = cnt[idx];
            offs[idx] = excl;
            cur[idx] = excl;
            excl += c;
        }
    }
}

// ---------------------------------------------------------------------------
// Scatter: 4 edges/thread, 4 independent atomic+store chains in flight.
// ---------------------------------------------------------------------------
__global__ __launch_bounds__(256) void scatter_kernel(
    const int* __restrict__ src, const int* __restrict__ dst,
    int* __restrict__ cur, int* __restrict__ eSrc, int E) {
    int e = (blockIdx.x * 256 + threadIdx.x) * 4;
    if (e + 3 < E) {
        int4 s4 = *(const int4*)(src + e);
        int4 d4 = *(const int4*)(dst + e);
        int p0 = atomicAdd(&cur[d4.x], 1);
        int p1 = atomicAdd(&cur[d4.y], 1);
        int p2 = atomicAdd(&cur[d4.z], 1);
        int p3 = atomicAdd(&cur[d4.w], 1);
        eSrc[p0] = s4.x;
        eSrc[p1] = s4.y;
        eSrc[p2] = s4.z;
        eSrc[p3] = s4.w;
    } else {
        for (int i = e; i < E; i++) {
            int pos = atomicAdd(&cur[dst[i]], 1);
            eSrc[pos] = src[i];
        }
    }
}

// ---------------------------------------------------------------------------
// Gather: one wave per dst node, lane owns 2 channels, unroll 8 for ILP.
// acc += relu(A[src] + B[dst]); writes X2 cols 0..127 bf16.
// ---------------------------------------------------------------------------
__global__ __launch_bounds__(256) void gather_kernel(
    const unsigned short* __restrict__ AB, const int* __restrict__ off,
    const int* __restrict__ cnt, const int* __restrict__ eSrc,
    unsigned short* __restrict__ X2, int N) {
    int wid = (blockIdx.x * 256 + threadIdx.x) >> 6;
    int lane = threadIdx.x & 63;
    if (wid >= N) return;
    int start = off[wid], num = cnt[wid];
    ushort2 bv = *(const ushort2*)(AB + (size_t)wid * 256 + 128 + lane * 2);
    float b0 = bf2f(bv.x), b1 = bf2f(bv.y);
    float a0 = 0.f, a1 = 0.f;

    for (int j0 = 0; j0 < num; j0 += 64) {
        int myIdx = j0 + lane;
        int mySrc = (myIdx < num) ? eSrc[start + myIdx] : 0;
        int lim = min(64, num - j0);
        int j = 0;
        for (; j + 8 <= lim; j += 8) {
            ushort2 v[8];
#pragma unroll
            for (int u = 0; u < 8; u++) {
                int s = __shfl(mySrc, j + u);
                v[u] = *(const ushort2*)(AB + (size_t)s * 256 + lane * 2);
            }
#pragma unroll
            for (int u = 0; u < 8; u++) {
                float x = bf2f(v[u].x) + b0;
                a0 += fmaxf(x, 0.f);
                float y = bf2f(v[u].y) + b1;
                a1 += fmaxf(y, 0.f);
            }
        }
        for (; j < lim; j++) {
            int s = __shfl(mySrc, j);
            ushort2 v = *(const ushort2*)(AB + (size_t)s * 256 + lane * 2);
            float x = bf2f(v.x) + b0;
            a0 += fmaxf(x, 0.f);
            float y = bf2f(v.y) + b1;
            a1 += fmaxf(y, 0.f);
        }
    }
    *(ushort2*)(X2 + (size_t)wid * 256 + lane * 2) = make_ushort2(f2bf(a0), f2bf(a1));
}

// ---------------------------------------------------------------------------
// 128x128-tile bf16 MFMA GEMM (unchanged from round 1).
// ---------------------------------------------------------------------------
template <bool OUT_BF16>
__global__ __launch_bounds__(256) void gemm128(
    const unsigned short* __restrict__ A, int lda,
    const unsigned short* __restrict__ Bt, int ldb, int nRowsB,
    void* __restrict__ Cout, int ldc,
    const float* __restrict__ bias, int M, int K) {
    __shared__ unsigned short As[128 * 128];
    __shared__ unsigned short Bs[128 * 128];
    const int tid = threadIdx.x;
    const int m0 = blockIdx.x * 128;
    const int n0 = blockIdx.y * 128;
    const int lane = tid & 63;
    const int w = tid >> 6;
    const int wr = w >> 1, wc = w & 1;
    const int q = lane >> 4, ln = lane & 15;

    f32x4 acc[4][4];
#pragma unroll
    for (int i = 0; i < 4; i++)
#pragma unroll
        for (int j = 0; j < 4; j++) acc[i][j] = (f32x4)0.f;

    for (int kk = 0; kk < K; kk += 128) {
#pragma unroll
        for (int i = 0; i < 8; i++) {
            int id = i * 256 + tid;
            int r = id >> 4, b = id & 15;
            ushort8v v = (ushort8v)(unsigned short)0;
            int gr = m0 + r;
            if (gr < M) v = *(const ushort8v*)(A + (size_t)gr * lda + kk + b * 8);
            *(ushort8v*)(As + r * 128 + ((b ^ (r & 15)) * 8)) = v;
        }
#pragma unroll
        for (int i = 0; i < 8; i++) {
            int id = i * 256 + tid;
            int r = id >> 4, b = id & 15;
            ushort8v v = (ushort8v)(unsigned short)0;
            int gr = n0 + r;
            if (gr < nRowsB) v = *(const ushort8v*)(Bt + (size_t)gr * ldb + kk + b * 8);
            *(ushort8v*)(Bs + r * 128 + ((b ^ (r & 15)) * 8)) = v;
        }
        __syncthreads();
#pragma unroll
        for (int ks = 0; ks < 4; ks++) {
            short8v af[4], bfv[4];
#pragma unroll
            for (int ti = 0; ti < 4; ti++) {
                int m = wr * 64 + ti * 16 + ln;
                int blk = (ks * 4 + q) ^ (m & 15);
                af[ti] = *(const short8v*)(As + m * 128 + blk * 8);
            }
#pragma unroll
            for (int tj = 0; tj < 4; tj++) {
                int n = wc * 64 + tj * 16 + ln;
                int blk = (ks * 4 + q) ^ (n & 15);
                bfv[tj] = *(const short8v*)(Bs + n * 128 + blk * 8);
            }
#pragma unroll
            for (int ti = 0; ti < 4; ti++)
#pragma unroll
                for (int tj = 0; tj < 4; tj++)
                    acc[ti][tj] = __builtin_amdgcn_mfma_f32_16x16x32_bf16(
                        af[ti], bfv[tj], acc[ti][tj], 0, 0, 0);
        }
        __syncthreads();
    }

#pragma unroll
    for (int ti = 0; ti < 4; ti++) {
        int rowb = m0 + wr * 64 + ti * 16 + q * 4;
#pragma unroll
        for (int tj = 0; tj < 4; tj++) {
            int col = n0 + wc * 64 + tj * 16 + ln;
            f32x4 c = acc[ti][tj];
            float bv = 0.f;
            if (!OUT_BF16 && bias) bv = bias[col];
#pragma unroll
            for (int r = 0; r < 4; r++) {
                int row = rowb + r;
                if (row < M) {
                    if (OUT_BF16)
                        ((unsigned short*)Cout)[(size_t)row * ldc + col] = f2bf(c[r]);
                    else
                        ((float*)Cout)[(size_t)row * ldc + col] = c[r] + bv;
                }
            }
        }
    }
}

// ---------------------------------------------------------------------------
extern "C" void kernel_launch(void* const* d_in, const int* in_sizes, int n_in,
                              void* d_out, int out_size, void* d_ws, size_t ws_size,
                              hipStream_t stream) {
    const float* feat = (const float*)d_in[0];
    const int* src = (const int*)d_in[1];
    const int* dst = (const int*)d_in[2];
    const float* W1 = (const float*)d_in[3];
    const float* W2 = (const float*)d_in[4];
    const float* LW = (const float*)d_in[5];
    const float* bias = (const float*)d_in[6];
    float* out = (float*)d_out;

    const int N = in_sizes[0] / 128;  // 50000
    const int E = in_sizes[1];        // 800000

    char* ws = (char*)d_ws;
    unsigned short* X2 = (unsigned short*)ws;            // [N,256] bf16: 0-127=S', 128-255=feat
    size_t off_b = (size_t)N * 256 * 2;
    unsigned short* AB = (unsigned short*)(ws + off_b);  // [N,256] bf16: A | B
    off_b += (size_t)N * 256 * 2;
    unsigned short* W1t = (unsigned short*)(ws + off_b);
    off_b += (size_t)256 * 128 * 2;
    unsigned short* W3t = (unsigned short*)(ws + off_b);
    off_b += (size_t)128 * 256 * 2;
    int* cnt = (int*)(ws + off_b);   off_b += (size_t)N * 4;
    int* offs = (int*)(ws + off_b);  off_b += (size_t)N * 4;
    int* cur = (int*)(ws + off_b);   off_b += (size_t)N * 4;
    int* eSrc = (int*)(ws + off_b);  off_b += (size_t)E * 4;

    int totalF = N * 128;
    int cvtB = (totalF / 4 + 255) / 256;
    int histB = ((E + 3) / 4 + 255) / 256;

    hipMemsetAsync(cnt, 0, (size_t)N * 4, stream);
    fused_pre<<<cvtB + histB + 256, 256, 0, stream>>>(
        feat, X2, totalF, dst, cnt, E, W1, W2, LW, W1t, W3t, cvtB, histB);
    scan_kernel<<<1, 1024, 0, stream>>>(cnt, offs, cur, N);
    scatter_kernel<<<((E + 3) / 4 + 255) / 256, 256, 0, stream>>>(src, dst, cur, eSrc, E);

    dim3 g1((N + 127) / 128, 2);
    gemm128<true><<<g1, 256, 0, stream>>>(X2 + 128, 256, W1t, 128, 256,
                                          (void*)AB, 256, nullptr, N, 128);

    gather_kernel<<<(N + 3) / 4, 256, 0, stream>>>(AB, offs, cnt, eSrc, X2, N);

    dim3 g2((N + 127) / 128, 1);
    gemm128<false><<<g2, 256, 0, stream>>>(X2, 256, W3t, 256, 128,
                                           (void*)out, 128, bias, N, 256);
}

// Round 4
// 249.250 us; speedup vs baseline: 1.4679x; 1.4679x over previous
//
#include <hip/hip_runtime.h>

typedef __attribute__((ext_vector_type(8))) unsigned short ushort8v;
typedef __attribute__((ext_vector_type(8))) short short8v;
typedef __attribute__((ext_vector_type(4))) float f32x4;

__device__ inline unsigned short f2bf(float f) {
    union { float f; unsigned u; } v; v.f = f;
    unsigned u = v.u;
    unsigned r = (u + 0x7FFFu + ((u >> 16) & 1u)) >> 16;
    return (unsigned short)r;
}
__device__ inline float bf2f(unsigned short h) {
    union { unsigned u; float f; } v; v.u = ((unsigned)h) << 16;
    return v.f;
}

// ---------------------------------------------------------------------------
// Fused pre-pass: [0, cvtB)   feat f32 -> X2 cols 128..255 bf16
//                 [cvtB, +histB) dst histogram, 4 edges/thread (int4, ILP)
//                 [cvtB+histB, +256) weight prep (W1t 256x128, W3t 128x256)
// ---------------------------------------------------------------------------
__global__ __launch_bounds__(256) void fused_pre(
    const float* __restrict__ feat, unsigned short* __restrict__ X2, int totalF,
    const int* __restrict__ dst, int* __restrict__ cnt, int E,
    const float* __restrict__ W1, const float* __restrict__ W2,
    const float* __restrict__ LW,
    unsigned short* __restrict__ W1t, unsigned short* __restrict__ W3t,
    int cvtB, int histB) {
    int b = blockIdx.x, t = threadIdx.x;
    if (b < cvtB) {
        int idx = (b * 256 + t) * 4;
        if (idx >= totalF) return;
        float4 v = *(const float4*)(feat + idx);
        int row = idx >> 7, col = idx & 127;
        unsigned short* o = X2 + (size_t)row * 256 + 128 + col;
        *(ushort4*)o = make_ushort4(f2bf(v.x), f2bf(v.y), f2bf(v.z), f2bf(v.w));
    } else if (b < cvtB + histB) {
        int e = ((b - cvtB) * 256 + t) * 4;
        if (e + 3 < E) {
            int4 d4 = *(const int4*)(dst + e);
            atomicAdd(&cnt[d4.x], 1);
            atomicAdd(&cnt[d4.y], 1);
            atomicAdd(&cnt[d4.z], 1);
            atomicAdd(&cnt[d4.w], 1);
        } else {
            for (int i = e; i < E; i++) atomicAdd(&cnt[dst[i]], 1);
        }
    } else {
        int i = (b - cvtB - histB) * 256 + t;  // 0..65535
        if (i < 32768) {
            int jj = i >> 7, k = i & 127;
            float v = (jj < 128) ? W1[k * 128 + jj] : W1[(128 + k) * 128 + (jj - 128)];
            W1t[i] = f2bf(v);
        } else {
            int i2 = i - 32768;
            int n = i2 >> 8, k = i2 & 255;
            float v = (k < 128) ? W2[k * 128 + n] : LW[(k - 128) * 128 + n];
            W3t[i2] = f2bf(v);
        }
    }
}

// ---------------------------------------------------------------------------
// 3-kernel exclusive scan (round-2 proven structure, int4 coalesced loads).
// ---------------------------------------------------------------------------
__global__ __launch_bounds__(256) void scan_reduce(
    const int* __restrict__ cnt, int* __restrict__ sums, int N) {
    __shared__ int l[256];
    int t = threadIdx.x, base = blockIdx.x * 1024;
    int idx = base + t * 4;
    int s = 0;
    if (idx + 3 < N) {
        int4 v = *(const int4*)(cnt + idx);
        s = v.x + v.y + v.z + v.w;
    } else {
        for (int i = 0; i < 4; i++)
            if (idx + i < N) s += cnt[idx + i];
    }
    l[t] = s;
    __syncthreads();
    for (int str = 128; str > 0; str >>= 1) {
        if (t < str) l[t] += l[t + str];
        __syncthreads();
    }
    if (t == 0) sums[blockIdx.x] = l[0];
}

__global__ __launch_bounds__(256) void scan_tops(int* __restrict__ sums, int NB) {
    __shared__ int l[256];
    int t = threadIdx.x;
    int orig = (t < NB) ? sums[t] : 0;
    l[t] = orig;
    __syncthreads();
    for (int off = 1; off < 256; off <<= 1) {
        int v = (t >= off) ? l[t - off] : 0;
        __syncthreads();
        l[t] += v;
        __syncthreads();
    }
    if (t < NB) sums[t] = l[t] - orig;
}

__global__ __launch_bounds__(256) void scan_final(
    const int* __restrict__ cnt, const int* __restrict__ sums,
    int* __restrict__ off, int* __restrict__ cur, int N) {
    __shared__ int l[256];
    int t = threadIdx.x, base = blockIdx.x * 1024;
    int idx = base + t * 4;
    int v[4];
    int s = 0;
    if (idx + 3 < N) {
        int4 q = *(const int4*)(cnt + idx);
        v[0] = q.x; v[1] = q.y; v[2] = q.z; v[3] = q.w;
        s = q.x + q.y + q.z + q.w;
    } else {
#pragma unroll
        for (int i = 0; i < 4; i++) {
            v[i] = (idx + i < N) ? cnt[idx + i] : 0;
            s += v[i];
        }
    }
    int orig = s;
    l[t] = s;
    __syncthreads();
    for (int o = 1; o < 256; o <<= 1) {
        int x = (t >= o) ? l[t - o] : 0;
        __syncthreads();
        l[t] += x;
        __syncthreads();
    }
    int excl = l[t] - orig + sums[blockIdx.x];
#pragma unroll
    for (int i = 0; i < 4; i++) {
        if (idx + i < N) { off[idx + i] = excl; cur[idx + i] = excl; }
        excl += v[i];
    }
}

// ---------------------------------------------------------------------------
// Scatter: 4 edges/thread, 4 independent atomic+store chains in flight.
// ---------------------------------------------------------------------------
__global__ __launch_bounds__(256) void scatter_kernel(
    const int* __restrict__ src, const int* __restrict__ dst,
    int* __restrict__ cur, int* __restrict__ eSrc, int E) {
    int e = (blockIdx.x * 256 + threadIdx.x) * 4;
    if (e + 3 < E) {
        int4 s4 = *(const int4*)(src + e);
        int4 d4 = *(const int4*)(dst + e);
        int p0 = atomicAdd(&cur[d4.x], 1);
        int p1 = atomicAdd(&cur[d4.y], 1);
        int p2 = atomicAdd(&cur[d4.z], 1);
        int p3 = atomicAdd(&cur[d4.w], 1);
        eSrc[p0] = s4.x;
        eSrc[p1] = s4.y;
        eSrc[p2] = s4.z;
        eSrc[p3] = s4.w;
    } else {
        for (int i = e; i < E; i++) {
            int pos = atomicAdd(&cur[dst[i]], 1);
            eSrc[pos] = src[i];
        }
    }
}

// ---------------------------------------------------------------------------
// Gather: one wave per dst node, lane owns 2 channels, unroll 8 for ILP.
// acc += relu(A[src] + B[dst]); writes X2 cols 0..127 bf16.
// ---------------------------------------------------------------------------
__global__ __launch_bounds__(256) void gather_kernel(
    const unsigned short* __restrict__ AB, const int* __restrict__ off,
    const int* __restrict__ cnt, const int* __restrict__ eSrc,
    unsigned short* __restrict__ X2, int N) {
    int wid = (blockIdx.x * 256 + threadIdx.x) >> 6;
    int lane = threadIdx.x & 63;
    if (wid >= N) return;
    int start = off[wid], num = cnt[wid];
    ushort2 bv = *(const ushort2*)(AB + (size_t)wid * 256 + 128 + lane * 2);
    float b0 = bf2f(bv.x), b1 = bf2f(bv.y);
    float a0 = 0.f, a1 = 0.f;

    for (int j0 = 0; j0 < num; j0 += 64) {
        int myIdx = j0 + lane;
        int mySrc = (myIdx < num) ? eSrc[start + myIdx] : 0;
        int lim = min(64, num - j0);
        int j = 0;
        for (; j + 8 <= lim; j += 8) {
            ushort2 v[8];
#pragma unroll
            for (int u = 0; u < 8; u++) {
                int s = __shfl(mySrc, j + u);
                v[u] = *(const ushort2*)(AB + (size_t)s * 256 + lane * 2);
            }
#pragma unroll
            for (int u = 0; u < 8; u++) {
                float x = bf2f(v[u].x) + b0;
                a0 += fmaxf(x, 0.f);
                float y = bf2f(v[u].y) + b1;
                a1 += fmaxf(y, 0.f);
            }
        }
        for (; j < lim; j++) {
            int s = __shfl(mySrc, j);
            ushort2 v = *(const ushort2*)(AB + (size_t)s * 256 + lane * 2);
            float x = bf2f(v.x) + b0;
            a0 += fmaxf(x, 0.f);
            float y = bf2f(v.y) + b1;
            a1 += fmaxf(y, 0.f);
        }
    }
    *(ushort2*)(X2 + (size_t)wid * 256 + lane * 2) = make_ushort2(f2bf(a0), f2bf(a1));
}

// ---------------------------------------------------------------------------
// 128x128-tile bf16 MFMA GEMM (unchanged).
// ---------------------------------------------------------------------------
template <bool OUT_BF16>
__global__ __launch_bounds__(256) void gemm128(
    const unsigned short* __restrict__ A, int lda,
    const unsigned short* __restrict__ Bt, int ldb, int nRowsB,
    void* __restrict__ Cout, int ldc,
    const float* __restrict__ bias, int M, int K) {
    __shared__ unsigned short As[128 * 128];
    __shared__ unsigned short Bs[128 * 128];
    const int tid = threadIdx.x;
    const int m0 = blockIdx.x * 128;
    const int n0 = blockIdx.y * 128;
    const int lane = tid & 63;
    const int w = tid >> 6;
    const int wr = w >> 1, wc = w & 1;
    const int q = lane >> 4, ln = lane & 15;

    f32x4 acc[4][4];
#pragma unroll
    for (int i = 0; i < 4; i++)
#pragma unroll
        for (int j = 0; j < 4; j++) acc[i][j] = (f32x4)0.f;

    for (int kk = 0; kk < K; kk += 128) {
#pragma unroll
        for (int i = 0; i < 8; i++) {
            int id = i * 256 + tid;
            int r = id >> 4, b = id & 15;
            ushort8v v = (ushort8v)(unsigned short)0;
            int gr = m0 + r;
            if (gr < M) v = *(const ushort8v*)(A + (size_t)gr * lda + kk + b * 8);
            *(ushort8v*)(As + r * 128 + ((b ^ (r & 15)) * 8)) = v;
        }
#pragma unroll
        for (int i = 0; i < 8; i++) {
            int id = i * 256 + tid;
            int r = id >> 4, b = id & 15;
            ushort8v v = (ushort8v)(unsigned short)0;
            int gr = n0 + r;
            if (gr < nRowsB) v = *(const ushort8v*)(Bt + (size_t)gr * ldb + kk + b * 8);
            *(ushort8v*)(Bs + r * 128 + ((b ^ (r & 15)) * 8)) = v;
        }
        __syncthreads();
#pragma unroll
        for (int ks = 0; ks < 4; ks++) {
            short8v af[4], bfv[4];
#pragma unroll
            for (int ti = 0; ti < 4; ti++) {
                int m = wr * 64 + ti * 16 + ln;
                int blk = (ks * 4 + q) ^ (m & 15);
                af[ti] = *(const short8v*)(As + m * 128 + blk * 8);
            }
#pragma unroll
            for (int tj = 0; tj < 4; tj++) {
                int n = wc * 64 + tj * 16 + ln;
                int blk = (ks * 4 + q) ^ (n & 15);
                bfv[tj] = *(const short8v*)(Bs + n * 128 + blk * 8);
            }
#pragma unroll
            for (int ti = 0; ti < 4; ti++)
#pragma unroll
                for (int tj = 0; tj < 4; tj++)
                    acc[ti][tj] = __builtin_amdgcn_mfma_f32_16x16x32_bf16(
                        af[ti], bfv[tj], acc[ti][tj], 0, 0, 0);
        }
        __syncthreads();
    }

#pragma unroll
    for (int ti = 0; ti < 4; ti++) {
        int rowb = m0 + wr * 64 + ti * 16 + q * 4;
#pragma unroll
        for (int tj = 0; tj < 4; tj++) {
            int col = n0 + wc * 64 + tj * 16 + ln;
            f32x4 c = acc[ti][tj];
            float bv = 0.f;
            if (!OUT_BF16 && bias) bv = bias[col];
#pragma unroll
            for (int r = 0; r < 4; r++) {
                int row = rowb + r;
                if (row < M) {
                    if (OUT_BF16)
                        ((unsigned short*)Cout)[(size_t)row * ldc + col] = f2bf(c[r]);
                    else
                        ((float*)Cout)[(size_t)row * ldc + col] = c[r] + bv;
                }
            }
        }
    }
}

// ---------------------------------------------------------------------------
extern "C" void kernel_launch(void* const* d_in, const int* in_sizes, int n_in,
                              void* d_out, int out_size, void* d_ws, size_t ws_size,
                              hipStream_t stream) {
    const float* feat = (const float*)d_in[0];
    const int* src = (const int*)d_in[1];
    const int* dst = (const int*)d_in[2];
    const float* W1 = (const float*)d_in[3];
    const float* W2 = (const float*)d_in[4];
    const float* LW = (const float*)d_in[5];
    const float* bias = (const float*)d_in[6];
    float* out = (float*)d_out;

    const int N = in_sizes[0] / 128;  // 50000
    const int E = in_sizes[1];        // 800000

    char* ws = (char*)d_ws;
    unsigned short* X2 = (unsigned short*)ws;            // [N,256] bf16: 0-127=S', 128-255=feat
    size_t off_b = (size_t)N * 256 * 2;
    unsigned short* AB = (unsigned short*)(ws + off_b);  // [N,256] bf16: A | B
    off_b += (size_t)N * 256 * 2;
    unsigned short* W1t = (unsigned short*)(ws + off_b);
    off_b += (size_t)256 * 128 * 2;
    unsigned short* W3t = (unsigned short*)(ws + off_b);
    off_b += (size_t)128 * 256 * 2;
    int* cnt = (int*)(ws + off_b);   off_b += (size_t)N * 4;
    int* offs = (int*)(ws + off_b);  off_b += (size_t)N * 4;
    int* cur = (int*)(ws + off_b);   off_b += (size_t)N * 4;
    int* sums = (int*)(ws + off_b);  off_b += 256 * 4;
    int* eSrc = (int*)(ws + off_b);  off_b += (size_t)E * 4;

    int totalF = N * 128;
    int cvtB = (totalF / 4 + 255) / 256;
    int histB = ((E + 3) / 4 + 255) / 256;
    const int NB = (N + 1023) / 1024;  // 49

    hipMemsetAsync(cnt, 0, (size_t)N * 4, stream);
    fused_pre<<<cvtB + histB + 256, 256, 0, stream>>>(
        feat, X2, totalF, dst, cnt, E, W1, W2, LW, W1t, W3t, cvtB, histB);
    scan_reduce<<<NB, 256, 0, stream>>>(cnt, sums, N);
    scan_tops<<<1, 256, 0, stream>>>(sums, NB);
    scan_final<<<NB, 256, 0, stream>>>(cnt, sums, offs, cur, N);
    scatter_kernel<<<((E + 3) / 4 + 255) / 256, 256, 0, stream>>>(src, dst, cur, eSrc, E);

    dim3 g1((N + 127) / 128, 2);
    gemm128<true><<<g1, 256, 0, stream>>>(X2 + 128, 256, W1t, 128, 256,
                                          (void*)AB, 256, nullptr, N, 128);

    gather_kernel<<<(N + 3) / 4, 256, 0, stream>>>(AB, offs, cnt, eSrc, X2, N);

    dim3 g2((N + 127) / 128, 1);
    gemm128<false><<<g2, 256, 0, stream>>>(X2, 256, W3t, 256, 128,
                                           (void*)out, 128, bias, N, 256);
}